// Round 1
// baseline (72681.116 us; speedup 1.0000x reference)
//
#include <hip/hip_runtime.h>

#define DD 1024        // hidden size
#define TT 8192        // sequence length
#define NBLK 128       // grid blocks (barrier participants)
#define NTHR 512       // 8 waves per block
#define RPB 8          // rows per block (one per wave)

__device__ __forceinline__ float fast_sigmoid(float x) {
  x = fminf(fmaxf(x, -30.0f), 30.0f);
  return 1.0f / (1.0f + __expf(-x));
}

__device__ __forceinline__ float fast_tanh(float x) {
  x = fminf(fmaxf(x, -15.0f), 15.0f);
  float e = __expf(2.0f * x);
  return (e - 1.0f) / (e + 1.0f);
}

// Sense-reversing grid barrier. count at bar[0], generation at bar[32]
// (separate 128B lines). AGENT scope => compiler emits the L2
// writeback/invalidate needed for cross-XCD visibility of the h/c stores.
__device__ __forceinline__ void grid_barrier(unsigned* bar, unsigned nblk) {
  __syncthreads();
  if (threadIdx.x == 0) {
    unsigned* cnt = bar;
    unsigned* gen = bar + 32;
    unsigned g = __hip_atomic_load(gen, __ATOMIC_RELAXED, __HIP_MEMORY_SCOPE_AGENT);
    unsigned prev = __hip_atomic_fetch_add(cnt, 1u, __ATOMIC_ACQ_REL, __HIP_MEMORY_SCOPE_AGENT);
    if (prev == nblk - 1u) {
      __hip_atomic_store(cnt, 0u, __ATOMIC_RELAXED, __HIP_MEMORY_SCOPE_AGENT);
      __hip_atomic_fetch_add(gen, 1u, __ATOMIC_RELEASE, __HIP_MEMORY_SCOPE_AGENT);
    } else {
      while (__hip_atomic_load(gen, __ATOMIC_ACQUIRE, __HIP_MEMORY_SCOPE_AGENT) == g) {
        __builtin_amdgcn_s_sleep(1);
      }
    }
  }
  __syncthreads();
}

// Persistent kernel: all 4 weight matrices live in VGPRs (128 floats/lane,
// 33.5MB across 65536 threads). Per step: broadcast-load h/x/c, 128 FMAs,
// 64-lane butterfly reduce, gates, store h_new/c_new, grid barrier.
__global__ __launch_bounds__(NTHR, 2) void lstm_seq(
    const float* __restrict__ X,      // [T, D] target_seq
    const float* __restrict__ enc_h,  // [D]
    const float* __restrict__ enc_c,  // [D]
    const float* __restrict__ Wf, const float* __restrict__ bf_,
    const float* __restrict__ Wi, const float* __restrict__ bi_,
    const float* __restrict__ Wc, const float* __restrict__ bc_,
    const float* __restrict__ Wo, const float* __restrict__ bo_,
    float* __restrict__ out,          // [T, D] predictions (h_t rows)
    float* __restrict__ cbuf,         // [2][D] double-buffered cell state
    unsigned* __restrict__ bar)
{
  const int wv   = threadIdx.x >> 6;   // wave id 0..7
  const int lane = threadIdx.x & 63;
  const int j    = blockIdx.x * RPB + wv;  // output row 0..1023

  // ---- preload weights into registers (once) ----
  float wfh[16], wfx[16], wih[16], wix[16], woh[16], wox[16], wch[16], wcc[16];
  const float* rf = Wf + (size_t)j * 2048;
  const float* ri = Wi + (size_t)j * 2048;
  const float* rc = Wc + (size_t)j * 2048;
  const float* ro = Wo + (size_t)j * 2048;
#pragma unroll
  for (int kb = 0; kb < 4; ++kb) {
    const int k = kb * 256 + lane * 4;
    const int b = kb * 4;
    *(float4*)&wfh[b] = *(const float4*)(rf + k);
    *(float4*)&wfx[b] = *(const float4*)(rf + 1024 + k);
    *(float4*)&wih[b] = *(const float4*)(ri + k);
    *(float4*)&wix[b] = *(const float4*)(ri + 1024 + k);
    *(float4*)&wch[b] = *(const float4*)(rc + k);
    *(float4*)&wcc[b] = *(const float4*)(rc + 1024 + k);
    *(float4*)&woh[b] = *(const float4*)(ro + k);
    *(float4*)&wox[b] = *(const float4*)(ro + 1024 + k);
  }
  const float Bf = bf_[j], Bi = bi_[j], Bc = bc_[j], Bo = bo_[j];

  for (int t = 0; t < TT; ++t) {
    const float* h    = (t == 0) ? enc_h : out + (size_t)(t - 1) * DD;
    const float* cvec = (t == 0) ? enc_c : cbuf + (size_t)(t & 1) * DD;
    const float* x    = X + (size_t)t * DD;

    float aF = 0.0f, aI = 0.0f, aO = 0.0f, aC = 0.0f;
#pragma unroll
    for (int kb = 0; kb < 4; ++kb) {
      const int k = kb * 256 + lane * 4;
      const int b = kb * 4;
      float4 hv = *(const float4*)(h + k);
      float4 xv = *(const float4*)(x + k);
      float4 cv = *(const float4*)(cvec + k);
      aF += wfh[b+0]*hv.x + wfh[b+1]*hv.y + wfh[b+2]*hv.z + wfh[b+3]*hv.w;
      aF += wfx[b+0]*xv.x + wfx[b+1]*xv.y + wfx[b+2]*xv.z + wfx[b+3]*xv.w;
      aI += wih[b+0]*hv.x + wih[b+1]*hv.y + wih[b+2]*hv.z + wih[b+3]*hv.w;
      aI += wix[b+0]*xv.x + wix[b+1]*xv.y + wix[b+2]*xv.z + wix[b+3]*xv.w;
      aO += woh[b+0]*hv.x + woh[b+1]*hv.y + woh[b+2]*hv.z + woh[b+3]*hv.w;
      aO += wox[b+0]*xv.x + wox[b+1]*xv.y + wox[b+2]*xv.z + wox[b+3]*xv.w;
      aC += wch[b+0]*hv.x + wch[b+1]*hv.y + wch[b+2]*hv.z + wch[b+3]*hv.w;
      aC += wcc[b+0]*cv.x + wcc[b+1]*cv.y + wcc[b+2]*cv.z + wcc[b+3]*cv.w;
    }
    // 64-lane butterfly reduce (all lanes end with the full sums)
#pragma unroll
    for (int m = 32; m >= 1; m >>= 1) {
      aF += __shfl_xor(aF, m, 64);
      aI += __shfl_xor(aI, m, 64);
      aO += __shfl_xor(aO, m, 64);
      aC += __shfl_xor(aC, m, 64);
    }

    const float cj = cvec[j];
    const float fg = fast_sigmoid(aF + Bf);
    const float ig = fast_sigmoid(aI + Bi);
    const float og = fast_sigmoid(aO + Bo);
    const float ct = fast_tanh(aC + Bc);
    const float cn = fg * cj + ig * ct;
    const float hn = og * fast_tanh(cn);

    if (lane == 0) {
      out[(size_t)t * DD + j] = hn;
      cbuf[(size_t)((t + 1) & 1) * DD + j] = cn;
    }
    grid_barrier(bar, NBLK);
  }
}

extern "C" void kernel_launch(void* const* d_in, const int* in_sizes, int n_in,
                              void* d_out, int out_size, void* d_ws, size_t ws_size,
                              hipStream_t stream) {
  const float* X    = (const float*)d_in[0];
  const float* eh   = (const float*)d_in[1];
  const float* ec   = (const float*)d_in[2];
  const float* Wf   = (const float*)d_in[3];
  const float* bf_  = (const float*)d_in[4];
  const float* Wi   = (const float*)d_in[5];
  const float* bi_  = (const float*)d_in[6];
  const float* Wc   = (const float*)d_in[7];
  const float* bc_  = (const float*)d_in[8];
  const float* Wo   = (const float*)d_in[9];
  const float* bo_  = (const float*)d_in[10];
  float* out = (float*)d_out;

  unsigned* bar = (unsigned*)d_ws;                    // 256 B
  float* cbuf   = (float*)((char*)d_ws + 256);        // 2*1024 floats

  // reset barrier state every call (captured into the graph => deterministic)
  hipMemsetAsync(d_ws, 0, 256, stream);

  void* args[] = {(void*)&X, (void*)&eh, (void*)&ec,
                  (void*)&Wf, (void*)&bf_, (void*)&Wi, (void*)&bi_,
                  (void*)&Wc, (void*)&bc_, (void*)&Wo, (void*)&bo_,
                  (void*)&out, (void*)&cbuf, (void*)&bar};
  hipError_t e = hipLaunchCooperativeKernel((const void*)lstm_seq,
                                            dim3(NBLK), dim3(NTHR),
                                            args, 0, stream);
  if (e != hipSuccess) {
    // fallback: plain launch (128 small blocks on 256 CUs are co-resident)
    lstm_seq<<<dim3(NBLK), dim3(NTHR), 0, stream>>>(X, eh, ec, Wf, bf_, Wi, bi_,
                                                    Wc, bc_, Wo, bo_, out, cbuf, bar);
  }
}

// Round 2
// 69926.727 us; speedup vs baseline: 1.0394x; 1.0394x over previous
//
#include <hip/hip_runtime.h>

#define DD 1024        // hidden size
#define TT 8192        // sequence length
#define NBLK 128       // grid blocks
#define NTHR 512       // 8 waves per block
#define RPB 8          // rows per block (one per wave)
#define FSP 128        // flag spacing in uints (512 B -> distinct lines/channels)

__device__ __forceinline__ float fast_sigmoid(float x) {
  x = fminf(fmaxf(x, -30.0f), 30.0f);
  return 1.0f / (1.0f + __expf(-x));
}

__device__ __forceinline__ float fast_tanh(float x) {
  x = fminf(fmaxf(x, -15.0f), 15.0f);
  float e = __expf(2.0f * x);
  return (e - 1.0f) / (e + 1.0f);
}

// Persistent kernel. Sync = flag array: block b release-stores flags[b*FSP]=t+1
// after finishing step t; at the top of step t every block's threads 0..127
// acquire-poll all 128 flags for >= t in parallel (O(1) barrier depth, zero
// atomic serialization), then __syncthreads.
__global__ __launch_bounds__(NTHR, 2) void lstm_seq(
    const float* __restrict__ X,      // [T, D]
    const float* __restrict__ enc_h,  // [D]
    const float* __restrict__ enc_c,  // [D]
    const float* __restrict__ Wf, const float* __restrict__ bf_,
    const float* __restrict__ Wi, const float* __restrict__ bi_,
    const float* __restrict__ Wc, const float* __restrict__ bc_,
    const float* __restrict__ Wo, const float* __restrict__ bo_,
    float* __restrict__ out,          // [T, D] h_t rows
    float* __restrict__ cbuf,         // c state slots (unique-per-step or ring-2)
    unsigned* __restrict__ flags,     // [NBLK * FSP]
    unsigned cmask)                   // TT-1 (unique) or 1 (ring-2)
{
  const int wv   = threadIdx.x >> 6;
  const int lane = threadIdx.x & 63;
  const int j    = blockIdx.x * RPB + wv;   // output row

  // ---- preload weights into registers (once) ----
  float wfh[16], wfx[16], wih[16], wix[16], woh[16], wox[16], wch[16], wcc[16];
  const float* rf = Wf + (size_t)j * 2048;
  const float* ri = Wi + (size_t)j * 2048;
  const float* rc = Wc + (size_t)j * 2048;
  const float* ro = Wo + (size_t)j * 2048;
#pragma unroll
  for (int kb = 0; kb < 4; ++kb) {
    const int k = kb * 256 + lane * 4;
    const int b = kb * 4;
    *(float4*)&wfh[b] = *(const float4*)(rf + k);
    *(float4*)&wfx[b] = *(const float4*)(rf + 1024 + k);
    *(float4*)&wih[b] = *(const float4*)(ri + k);
    *(float4*)&wix[b] = *(const float4*)(ri + 1024 + k);
    *(float4*)&wch[b] = *(const float4*)(rc + k);
    *(float4*)&wcc[b] = *(const float4*)(rc + 1024 + k);
    *(float4*)&woh[b] = *(const float4*)(ro + k);
    *(float4*)&wox[b] = *(const float4*)(ro + 1024 + k);
  }
  // Force weights to be VGPR-resident (prevents the compiler from sinking the
  // loads back into the t-loop — round-1 showed VGPR_Count=100, i.e. demoted).
#pragma unroll
  for (int i = 0; i < 16; ++i) {
    asm volatile("" : "+v"(wfh[i]), "+v"(wfx[i]), "+v"(wih[i]), "+v"(wix[i]),
                      "+v"(woh[i]), "+v"(wox[i]), "+v"(wch[i]), "+v"(wcc[i]));
  }
  const float Bf = bf_[j], Bi = bi_[j], Bc = bc_[j], Bo = bo_[j];

  for (int t = 0; t < TT; ++t) {
    // prefetch x_t (recurrence-independent) before waiting
    float4 xv0, xv1, xv2, xv3;
    {
      const float* x = X + (size_t)t * DD + lane * 4;
      xv0 = *(const float4*)(x);
      xv1 = *(const float4*)(x + 256);
      xv2 = *(const float4*)(x + 512);
      xv3 = *(const float4*)(x + 768);
    }

    if (t > 0) {
      if (threadIdx.x < NBLK) {
        while (__hip_atomic_load(&flags[threadIdx.x * FSP], __ATOMIC_ACQUIRE,
                                 __HIP_MEMORY_SCOPE_AGENT) < (unsigned)t) {
          __builtin_amdgcn_s_sleep(1);
        }
      }
      __syncthreads();
    }

    const float* h    = (t == 0) ? enc_h : out + (size_t)(t - 1) * DD;
    const float* cvec = (t == 0) ? enc_c : cbuf + (size_t)((t - 1) & cmask) * DD;

    const float cj = cvec[j];
    float aF = 0.0f, aI = 0.0f, aO = 0.0f, aC = 0.0f;
#pragma unroll
    for (int kb = 0; kb < 4; ++kb) {
      const int k = kb * 256 + lane * 4;
      const int b = kb * 4;
      float4 hv = *(const float4*)(h + k);
      float4 cv = *(const float4*)(cvec + k);
      float4 xv = (kb == 0) ? xv0 : (kb == 1) ? xv1 : (kb == 2) ? xv2 : xv3;
      aF += wfh[b+0]*hv.x + wfh[b+1]*hv.y + wfh[b+2]*hv.z + wfh[b+3]*hv.w;
      aF += wfx[b+0]*xv.x + wfx[b+1]*xv.y + wfx[b+2]*xv.z + wfx[b+3]*xv.w;
      aI += wih[b+0]*hv.x + wih[b+1]*hv.y + wih[b+2]*hv.z + wih[b+3]*hv.w;
      aI += wix[b+0]*xv.x + wix[b+1]*xv.y + wix[b+2]*xv.z + wix[b+3]*xv.w;
      aO += woh[b+0]*hv.x + woh[b+1]*hv.y + woh[b+2]*hv.z + woh[b+3]*hv.w;
      aO += wox[b+0]*xv.x + wox[b+1]*xv.y + wox[b+2]*xv.z + wox[b+3]*xv.w;
      aC += wch[b+0]*hv.x + wch[b+1]*hv.y + wch[b+2]*hv.z + wch[b+3]*hv.w;
      aC += wcc[b+0]*cv.x + wcc[b+1]*cv.y + wcc[b+2]*cv.z + wcc[b+3]*cv.w;
    }
#pragma unroll
    for (int m = 32; m >= 1; m >>= 1) {
      aF += __shfl_xor(aF, m, 64);
      aI += __shfl_xor(aI, m, 64);
      aO += __shfl_xor(aO, m, 64);
      aC += __shfl_xor(aC, m, 64);
    }

    const float fg = fast_sigmoid(aF + Bf);
    const float ig = fast_sigmoid(aI + Bi);
    const float og = fast_sigmoid(aO + Bo);
    const float ct = fast_tanh(aC + Bc);
    const float cn = fg * cj + ig * ct;
    const float hn = og * fast_tanh(cn);

    if (lane == 0) {
      out[(size_t)t * DD + j] = hn;
      cbuf[(size_t)(t & cmask) * DD + j] = cn;
    }
    __syncthreads();  // waits vmcnt(0): all 8 waves' stores are in L2
    if (threadIdx.x == 0) {
      __hip_atomic_store(&flags[blockIdx.x * FSP], (unsigned)(t + 1),
                         __ATOMIC_RELEASE, __HIP_MEMORY_SCOPE_AGENT);
    }
  }
}

extern "C" void kernel_launch(void* const* d_in, const int* in_sizes, int n_in,
                              void* d_out, int out_size, void* d_ws, size_t ws_size,
                              hipStream_t stream) {
  const float* X    = (const float*)d_in[0];
  const float* eh   = (const float*)d_in[1];
  const float* ec   = (const float*)d_in[2];
  const float* Wf   = (const float*)d_in[3];
  const float* bf_  = (const float*)d_in[4];
  const float* Wi   = (const float*)d_in[5];
  const float* bi_  = (const float*)d_in[6];
  const float* Wc   = (const float*)d_in[7];
  const float* bc_  = (const float*)d_in[8];
  const float* Wo   = (const float*)d_in[9];
  const float* bo_  = (const float*)d_in[10];
  float* out = (float*)d_out;

  const size_t flagsz = (size_t)NBLK * FSP * sizeof(unsigned);  // 64 KB
  unsigned* flags = (unsigned*)d_ws;
  float* cbuf = (float*)((char*)d_ws + flagsz);
  // unique c-slot per step if workspace allows (airtight vs line-reuse
  // coherence); else ring-2 (validated in round 1)
  const size_t cneed = (size_t)TT * DD * sizeof(float);
  unsigned cmask = (ws_size >= flagsz + cneed) ? (unsigned)(TT - 1) : 1u;

  hipMemsetAsync(d_ws, 0, flagsz, stream);

  void* args[] = {(void*)&X, (void*)&eh, (void*)&ec,
                  (void*)&Wf, (void*)&bf_, (void*)&Wi, (void*)&bi_,
                  (void*)&Wc, (void*)&bc_, (void*)&Wo, (void*)&bo_,
                  (void*)&out, (void*)&cbuf, (void*)&flags, (void*)&cmask};
  hipError_t e = hipLaunchCooperativeKernel((const void*)lstm_seq,
                                            dim3(NBLK), dim3(NTHR),
                                            args, 0, stream);
  if (e != hipSuccess) {
    lstm_seq<<<dim3(NBLK), dim3(NTHR), 0, stream>>>(X, eh, ec, Wf, bf_, Wi, bi_,
                                                    Wc, bc_, Wo, bo_, out, cbuf,
                                                    flags, cmask);
  }
}